// Round 8
// baseline (184.829 us; speedup 1.0000x reference)
//
#include <hip/hip_runtime.h>
#include <math.h>

// Problem constants
#define NB 32
#define CI 64
#define CO 64
#define CA 16
#define NK 4
#define HH 128
#define WW 128
#define EPSBN 1e-5f

typedef __bf16 bf16x8 __attribute__((ext_vector_type(8)));
typedef float f32x4 __attribute__((ext_vector_type(4)));

__device__ inline unsigned short f2bf(float f) {
    union { float f; unsigned u; } c; c.f = f;
    return (unsigned short)((c.u + 0x7fffu + ((c.u >> 16) & 1u)) >> 16);
}

// packed 2xf32 -> 2xbf16 (lo = first arg), single VALU op
__device__ inline unsigned cvt_pk_bf16(float lo, float hi) {
    unsigned r;
    asm("v_cvt_pk_bf16_f32 %0, %1, %2" : "=v"(r) : "v"(lo), "v"(hi));
    return r;
}

__device__ inline void gload_lds16(const void* g, void* l) {
    __builtin_amdgcn_global_load_lds(
        (const __attribute__((address_space(1))) unsigned int*)g,
        (__attribute__((address_space(3))) unsigned int*)l, 16, 0, 0);
}

// Workspace layout (float offsets). Total 70.5 MB (proven available).
#define WS_ZERO  0              // 64 (zero page for OOB redirect)
#define WS_CHA   64             // 2048
#define WS_FA    2112           // 2048
#define WS_KA    4160           // 128
#define WS_SP    4288           // 288
#define WS_PART  8192           // 32*64*16 = 32768 used
#define WS_W2T   270336         // 1179648 ushorts
#define WS_XT    860160         // 33554432 ushorts

// ===========================================================================
// 1) Register transpose + pooled partials. Block = (hg of 8 rows, b), 256 thr
//    = 4 waves (ci-half x row-quad). Lane owns a w-PAIR (float2 loads, 8B/lane),
//    packs via v_cvt_pk_bf16_f32, stores 2x64B NHWC per row. Pool sums in
//    registers across rows; one LDS reduce per block.
// ===========================================================================
__global__ __launch_bounds__(256) void transpose_pool(const float* __restrict__ x,
                                                      unsigned short* __restrict__ xt,
                                                      float* __restrict__ partial,
                                                      float* __restrict__ zeros) {
    __shared__ float vs[64 * 129];
    __shared__ float red[64 * 4];
    const int tid = threadIdx.x;
    const int hg = blockIdx.x;       // 0..15 (8 rows each)
    const int b  = blockIdx.y;
    const int lane = tid & 63;
    const int wv  = tid >> 6;
    const int cih = wv & 1;
    const int rq  = wv >> 1;         // row quad: rows rq*4 .. rq*4+3

    if (hg == 0 && b == 0 && tid < 64) zeros[tid] = 0.f;   // zero page for conv

    float sum[32];
    #pragma unroll
    for (int i = 0; i < 32; ++i) sum[i] = 0.f;

    #pragma unroll 1
    for (int j = 0; j < 4; ++j) {
        const int h = hg * 8 + rq * 4 + j;
        const float* xp = x + ((size_t)(b * CI + cih * 32) * HH + h) * WW + 2 * lane;
        float2 v[32];
        #pragma unroll
        for (int i = 0; i < 32; ++i) v[i] = *(const float2*)(xp + (size_t)i * (HH * WW));
        #pragma unroll
        for (int i = 0; i < 32; ++i) sum[i] += v[i].x + v[i].y;
        unsigned q0[16], q1[16];
        #pragma unroll
        for (int i = 0; i < 16; ++i) {
            q0[i] = cvt_pk_bf16(v[2 * i].x, v[2 * i + 1].x);
            q1[i] = cvt_pk_bf16(v[2 * i].y, v[2 * i + 1].y);
        }
        unsigned short* dst = xt + ((size_t)(b * HH + h) * WW + 2 * lane) * CI + cih * 32;
        #pragma unroll
        for (int k = 0; k < 4; ++k)
            ((uint4*)dst)[k] = make_uint4(q0[4*k], q0[4*k+1], q0[4*k+2], q0[4*k+3]);
        unsigned short* dst1 = dst + CI;
        #pragma unroll
        for (int k = 0; k < 4; ++k)
            ((uint4*)dst1)[k] = make_uint4(q1[4*k], q1[4*k+1], q1[4*k+2], q1[4*k+3]);
    }

    // col slot = rq*64 + lane (unique 0..127 across the 2 row-quads)
    #pragma unroll
    for (int i = 0; i < 32; ++i) vs[(cih * 32 + i) * 129 + rq * 64 + lane] = sum[i];
    __syncthreads();
    {
        const int ci = tid & 63, qd = tid >> 6;
        float s = 0.f;
        #pragma unroll
        for (int e = 0; e < 32; ++e) s += vs[ci * 129 + qd * 32 + e];
        red[ci * 4 + qd] = s;
    }
    __syncthreads();
    if (tid < 64)
        partial[((size_t)b * CI + tid) * 16 + hg] =
            red[tid * 4] + red[tid * 4 + 1] + red[tid * 4 + 2] + red[tid * 4 + 3];
}

// ===========================================================================
// 2) attention: reduce partials (16 hg, contiguous) + trunk + 4 heads.
// ===========================================================================
__global__ __launch_bounds__(512) void attn3(
    const float* __restrict__ partial, const float* __restrict__ prep_w,
    const float* __restrict__ bn_g, const float* __restrict__ bn_b,
    const float* __restrict__ bn_m, const float* __restrict__ bn_v,
    const float* __restrict__ fc_sp_w, const float* __restrict__ fc_sp_b,
    const float* __restrict__ fc_ch_w, const float* __restrict__ fc_ch_b,
    const float* __restrict__ fc_f_w,  const float* __restrict__ fc_f_b,
    const float* __restrict__ fc_k_w,  const float* __restrict__ fc_k_b,
    float* __restrict__ sp, float* __restrict__ cha,
    float* __restrict__ fa, float* __restrict__ ka) {
    __shared__ float pooled_s[NB * CI];
    __shared__ float att_s[NB * CA];
    const int tid = threadIdx.x;
    const float scale = 1.f / (HH * WW);
    #pragma unroll
    for (int i = 0; i < 4; ++i) {
        const int e = tid + 512 * i;
        const float4* pp = (const float4*)(partial + (size_t)e * 16);
        float s = 0.f;
        #pragma unroll
        for (int j = 0; j < 4; ++j) { float4 v = pp[j]; s += v.x + v.y + v.z + v.w; }
        pooled_s[e] = s;
    }
    __syncthreads();
    const int b = tid >> 4, a = tid & 15;
    {
        float s = 0.f;
        const float* pv = pooled_s + b * CI;
        #pragma unroll
        for (int c = 0; c < CI; ++c) s += pv[c] * prep_w[a * CI + c];
        s = (s * scale - bn_m[a]) * rsqrtf(bn_v[a] + EPSBN) * bn_g[a] + bn_b[a];
        att_s[b * CA + a] = fmaxf(s, 0.f);
    }
    __syncthreads();
    float av[CA];
    #pragma unroll
    for (int i = 0; i < CA; ++i) av[i] = att_s[b * CA + i];

    const int j = a;
    if (j < 9) {
        float s = fc_sp_b[j];
        #pragma unroll
        for (int i = 0; i < CA; ++i) s += av[i] * fc_sp_w[j * CA + i];
        sp[b * 9 + j] = 1.f / (1.f + expf(-s));
    }
    #pragma unroll
    for (int t = 0; t < 4; ++t) {
        const int c = j * 4 + t;
        float s1 = fc_ch_b[c], s2 = fc_f_b[c];
        #pragma unroll
        for (int i = 0; i < CA; ++i) {
            s1 += av[i] * fc_ch_w[c * CA + i];
            s2 += av[i] * fc_f_w[c * CA + i];
        }
        cha[b * CI + c] = 1.f / (1.f + expf(-s1));
        fa[b * CO + c]  = 1.f / (1.f + expf(-s2));
    }
    if (j == 0) {
        float kv[NK], m = -1e30f;
        #pragma unroll
        for (int k = 0; k < NK; ++k) {
            float s = fc_k_b[k];
            #pragma unroll
            for (int i = 0; i < CA; ++i) s += av[i] * fc_k_w[k * CA + i];
            kv[k] = s; m = fmaxf(m, s);
        }
        float den = 0.f;
        #pragma unroll
        for (int k = 0; k < NK; ++k) { kv[k] = expf(kv[k] - m); den += kv[k]; }
        #pragma unroll
        for (int k = 0; k < NK; ++k) ka[b * NK + k] = kv[k] / den;
    }
}

// ===========================================================================
// 3) folded weights w2t[b][tap][o][i] bf16 (lanes = i: 128B-line writes)
// ===========================================================================
__global__ __launch_bounds__(256) void w2t2(const float* __restrict__ kernels,
                                            const float* __restrict__ sp,
                                            const float* __restrict__ cha,
                                            const float* __restrict__ fa,
                                            const float* __restrict__ ka,
                                            unsigned short* __restrict__ w2t) {
    const int bid = blockIdx.x;              // 32*16
    const int b  = bid >> 4;
    const int o  = (bid & 15) * 4 + (threadIdx.x >> 6);
    const int i  = threadIdx.x & 63;
    float kw[NK][9];
    #pragma unroll
    for (int k = 0; k < NK; ++k) {
        const float* kp = kernels + ((size_t)(k * CO + o) * CI + i) * 9;
        #pragma unroll
        for (int t = 0; t < 9; ++t) kw[k][t] = kp[t];
    }
    float kav[NK];
    #pragma unroll
    for (int k = 0; k < NK; ++k) kav[k] = ka[b * NK + k];
    const float base = cha[b * CI + i] * fa[b * CO + o];
    #pragma unroll
    for (int tap = 0; tap < 9; ++tap) {
        float s = 0.f;
        #pragma unroll
        for (int k = 0; k < NK; ++k) s += kav[k] * kw[k][tap];
        w2t[((size_t)(b * 9 + tap) * CO + o) * CI + i] = f2bf(s * sp[b * 9 + tap] * base);
    }
}

// ===========================================================================
// 4) LDS-staged conv (mfma_f32_16x16x32_bf16), 256 thr / 4 waves,
//    64co x 32col x 4row per block; x-tile 6r x 34c x 64ci bf16 (26.6KB LDS,
//    oct-XOR swizzle baked into source addr, zero-page OOB redirect).
//    A-fragments live fully in registers as two static ks-halves:
//    ks0 issued BEFORE the staging barrier (overlaps drain), ks1 between
//    halves (hidden under ks0's 72 MFMAs / hoisted by scheduler).
// ===========================================================================
__global__ __launch_bounds__(256, 3) void conv_lds(const unsigned short* __restrict__ xt,
                                                   const unsigned short* __restrict__ w2t,
                                                   const unsigned short* __restrict__ zeros,
                                                   float* __restrict__ out) {
    __shared__ __align__(16) unsigned char xs[26624];   // 26 chunks x 1024B
    const int tid  = threadIdx.x;
    const int lane = tid & 63;
    const int wv   = tid >> 6;
    const int orig = blockIdx.x;
    const int bid  = (orig & 7) * 512 + (orig >> 3);    // XCD swizzle (4096 = 8*512)
    const int b    = bid >> 7;
    const int rem  = bid & 127;
    const int hg   = rem >> 2;
    const int colg = rem & 3;
    const int h0 = hg * 4;
    const int w0 = colg * 32;

    const unsigned short* xb = xt + (size_t)b * (HH * WW * CI);

    // ---- stage: 6r x 34c x 8oct = 1632 16B-units (26 chunks, tail zero-padded)
    for (int chunk = wv; chunk < 26; chunk += 4) {
        const int unit = (chunk << 6) + lane;
        const int row  = (int)((unsigned)unit / 272u);
        const int rr   = unit - row * 272;
        const int col  = rr >> 3;
        const int q    = rr & 7;
        const int hh = h0 - 1 + row;
        const int wc = w0 - 1 + col;
        const unsigned short* g = zeros;
        if (unit < 1632 && (unsigned)hh < (unsigned)HH && (unsigned)wc < (unsigned)WW)
            g = xb + (((size_t)hh << 7) + (size_t)wc) * 64 + ((q ^ (col & 7)) << 3);
        gload_lds16(g, xs + (chunk << 10));
    }

    const int cl = lane & 15;        // pixel col in 16 / o in 16
    const int kq = lane >> 4;        // k-quarter (8 ci)
    const int cohalf = wv & 1;
    const int colh   = wv >> 1;      // 0..1

    const unsigned short* w2b = w2t + (size_t)b * (9 * 4096)
                              + (size_t)(cohalf * 32) * 64 + kq * 8;

    // ks=0 A-half: in flight during the staging drain
    bf16x8 A0[3][3][2];
    #pragma unroll
    for (int v = 0; v < 3; ++v)
        #pragma unroll
        for (int u = 0; u < 3; ++u)
            #pragma unroll
            for (int og = 0; og < 2; ++og)
                A0[v][u][og] = *(const bf16x8*)(w2b + (size_t)(u * 3 + v) * 4096
                                                + (og * 16 + cl) * 64);
    __syncthreads();

    f32x4 acc[2][4];
    #pragma unroll
    for (int og = 0; og < 2; ++og)
        #pragma unroll
        for (int t = 0; t < 4; ++t)
            #pragma unroll
            for (int e = 0; e < 4; ++e) acc[og][t][e] = 0.f;

    // ---- ks = 0 compute
    #pragma unroll
    for (int v = 0; v < 3; ++v) {
        const int lcol = colh * 16 + cl + v;          // 0..33
        const int sw = kq ^ (lcol & 7);               // ks=0 oct
        const unsigned char* bp = xs + (((lcol << 3) + sw) << 4);
        bf16x8 Bf[6];
        #pragma unroll
        for (int r = 0; r < 6; ++r) Bf[r] = *(const bf16x8*)(bp + r * 4352);
        __builtin_amdgcn_s_setprio(1);
        #pragma unroll
        for (int u = 0; u < 3; ++u)
            #pragma unroll
            for (int og = 0; og < 2; ++og)
                #pragma unroll
                for (int t = 0; t < 4; ++t)
                    acc[og][t] = __builtin_amdgcn_mfma_f32_16x16x32_bf16(
                        A0[v][u][og], Bf[t + u], acc[og][t], 0, 0, 0);
        __builtin_amdgcn_s_setprio(0);
    }

    // ks=1 A-half (scheduler may hoist into ks0's MFMA region)
    bf16x8 A1[3][3][2];
    #pragma unroll
    for (int v = 0; v < 3; ++v)
        #pragma unroll
        for (int u = 0; u < 3; ++u)
            #pragma unroll
            for (int og = 0; og < 2; ++og)
                A1[v][u][og] = *(const bf16x8*)(w2b + (size_t)(u * 3 + v) * 4096 + 32
                                                + (og * 16 + cl) * 64);

    // ---- ks = 1 compute
    #pragma unroll
    for (int v = 0; v < 3; ++v) {
        const int lcol = colh * 16 + cl + v;
        const int sw = (4 + kq) ^ (lcol & 7);         // ks=1 oct
        const unsigned char* bp = xs + (((lcol << 3) + sw) << 4);
        bf16x8 Bf[6];
        #pragma unroll
        for (int r = 0; r < 6; ++r) Bf[r] = *(const bf16x8*)(bp + r * 4352);
        __builtin_amdgcn_s_setprio(1);
        #pragma unroll
        for (int u = 0; u < 3; ++u)
            #pragma unroll
            for (int og = 0; og < 2; ++og)
                #pragma unroll
                for (int t = 0; t < 4; ++t)
                    acc[og][t] = __builtin_amdgcn_mfma_f32_16x16x32_bf16(
                        A1[v][u][og], Bf[t + u], acc[og][t], 0, 0, 0);
        __builtin_amdgcn_s_setprio(0);
    }

    // ---- epilogue: C/D row (co-in-16) = kq*4 + rg, col = cl
    #pragma unroll
    for (int og = 0; og < 2; ++og)
        #pragma unroll
        for (int t = 0; t < 4; ++t) {
            float* op = out + ((size_t)(b * CO + cohalf * 32 + og * 16 + kq * 4) * HH + h0 + t) * WW
                      + w0 + colh * 16 + cl;
            #pragma unroll
            for (int rg = 0; rg < 4; ++rg)
                op[(size_t)rg * (HH * WW)] = acc[og][t][rg];
        }
}

// ===========================================================================
extern "C" void kernel_launch(void* const* d_in, const int* in_sizes, int n_in,
                              void* d_out, int out_size, void* d_ws, size_t ws_size,
                              hipStream_t stream) {
    const float* x        = (const float*)d_in[0];
    const float* prep_w   = (const float*)d_in[1];
    const float* bn_g     = (const float*)d_in[2];
    const float* bn_b     = (const float*)d_in[3];
    const float* bn_m     = (const float*)d_in[4];
    const float* bn_v     = (const float*)d_in[5];
    const float* fc_sp_w  = (const float*)d_in[6];
    const float* fc_sp_b  = (const float*)d_in[7];
    const float* fc_ch_w  = (const float*)d_in[8];
    const float* fc_ch_b  = (const float*)d_in[9];
    const float* fc_f_w   = (const float*)d_in[10];
    const float* fc_f_b   = (const float*)d_in[11];
    const float* fc_k_w   = (const float*)d_in[12];
    const float* fc_k_b   = (const float*)d_in[13];
    const float* kernels  = (const float*)d_in[14];
    float* out = (float*)d_out;
    float* ws  = (float*)d_ws;

    float* zeros   = ws + WS_ZERO;
    float* cha     = ws + WS_CHA;
    float* fa      = ws + WS_FA;
    float* ka      = ws + WS_KA;
    float* sp      = ws + WS_SP;
    float* partial = ws + WS_PART;
    unsigned short* w2t = (unsigned short*)(ws + WS_W2T);
    unsigned short* xt  = (unsigned short*)(ws + WS_XT);

    transpose_pool<<<dim3(16, NB), 256, 0, stream>>>(x, xt, partial, zeros);
    attn3<<<1, 512, 0, stream>>>(partial, prep_w, bn_g, bn_b, bn_m, bn_v,
                                 fc_sp_w, fc_sp_b, fc_ch_w, fc_ch_b,
                                 fc_f_w, fc_f_b, fc_k_w, fc_k_b,
                                 sp, cha, fa, ka);
    w2t2<<<NB * 16, 256, 0, stream>>>(kernels, sp, cha, fa, ka, w2t);
    conv_lds<<<4096, 256, 0, stream>>>(xt, w2t, (const unsigned short*)zeros, out);
}

// Round 9
// 149.162 us; speedup vs baseline: 1.2391x; 1.2391x over previous
//
#include <hip/hip_runtime.h>
#include <math.h>

// Problem constants
#define NB 32
#define CI 64
#define CO 64
#define CA 16
#define NK 4
#define HH 128
#define WW 128
#define EPSBN 1e-5f

typedef __bf16 bf16x8 __attribute__((ext_vector_type(8)));
typedef float f32x4 __attribute__((ext_vector_type(4)));

__device__ inline unsigned short f2bf(float f) {
    union { float f; unsigned u; } c; c.f = f;
    return (unsigned short)((c.u + 0x7fffu + ((c.u >> 16) & 1u)) >> 16);
}

// packed 2xf32 -> 2xbf16 (lo = first arg), single VALU op
__device__ inline unsigned cvt_pk_bf16(float lo, float hi) {
    unsigned r;
    asm("v_cvt_pk_bf16_f32 %0, %1, %2" : "=v"(r) : "v"(lo), "v"(hi));
    return r;
}

__device__ inline void gload_lds16(const void* g, void* l) {
    __builtin_amdgcn_global_load_lds(
        (const __attribute__((address_space(1))) unsigned int*)g,
        (__attribute__((address_space(3))) unsigned int*)l, 16, 0, 0);
}

// Workspace layout (float offsets). Total 70.5 MB (proven available).
#define WS_ZERO  0              // 64 (zero page for OOB redirect)
#define WS_CHA   64             // 2048
#define WS_FA    2112           // 2048
#define WS_KA    4160           // 128
#define WS_SP    4288           // 288
#define WS_PART  8192           // 32*64*64 = 131072 used
#define WS_W2T   270336         // 1179648 ushorts
#define WS_XT    860160         // 33554432 ushorts

// ===========================================================================
// 1) Register transpose + pooled partials. Block = (hg2 of 2 rows, b), 256 thr
//    = 4 waves (ci-half x w-half). Lane owns one w (4B loads, 32 planes/row);
//    packs via v_cvt_pk_bf16_f32, stores 64B NHWC per row. Pool sums in regs;
//    3-step shfl_xor octet pre-reduce -> 4.3KB LDS -> 8 blocks/CU.
// ===========================================================================
__global__ __launch_bounds__(256) void transpose_pool(const float* __restrict__ x,
                                                      unsigned short* __restrict__ xt,
                                                      float* __restrict__ partial,
                                                      float* __restrict__ zeros) {
    __shared__ float redl[64 * 17];
    const int tid = threadIdx.x;
    const int hg2 = blockIdx.x;      // 0..63 (2 rows each)
    const int b   = blockIdx.y;
    const int lane = tid & 63;
    const int wv  = tid >> 6;
    const int cih = wv & 1;
    const int wh  = wv >> 1;
    const int w = wh * 64 + lane;

    if (hg2 == 0 && b == 0 && tid < 64) zeros[tid] = 0.f;   // zero page for conv

    float sum[32];
    #pragma unroll
    for (int i = 0; i < 32; ++i) sum[i] = 0.f;

    #pragma unroll 1
    for (int j = 0; j < 2; ++j) {
        const int h = hg2 * 2 + j;
        const float* xp = x + ((size_t)(b * CI + cih * 32) * HH + h) * WW + w;
        float vals[32];
        #pragma unroll
        for (int i = 0; i < 32; ++i) vals[i] = xp[(size_t)i * (HH * WW)];
        #pragma unroll
        for (int i = 0; i < 32; ++i) sum[i] += vals[i];
        unsigned q[16];
        #pragma unroll
        for (int i = 0; i < 16; ++i) q[i] = cvt_pk_bf16(vals[2 * i], vals[2 * i + 1]);
        unsigned short* dst = xt + ((size_t)(b * HH + h) * WW + w) * CI + cih * 32;
        #pragma unroll
        for (int k = 0; k < 4; ++k)
            ((uint4*)dst)[k] = make_uint4(q[4*k], q[4*k+1], q[4*k+2], q[4*k+3]);
    }

    // octet pre-reduce over lane bits 0..2 (w within octet)
    #pragma unroll
    for (int mask = 1; mask <= 4; mask <<= 1)
        #pragma unroll
        for (int i = 0; i < 32; ++i) sum[i] += __shfl_xor(sum[i], mask, 64);

    if ((lane & 7) == 0) {
        const int wslot = wh * 8 + (lane >> 3);     // 0..15
        #pragma unroll
        for (int i = 0; i < 32; ++i) redl[(cih * 32 + i) * 17 + wslot] = sum[i];
    }
    __syncthreads();
    if (tid < 64) {
        float s = 0.f;
        #pragma unroll
        for (int k = 0; k < 16; ++k) s += redl[tid * 17 + k];
        partial[((size_t)b * CI + tid) * 64 + hg2] = s;
    }
}

// ===========================================================================
// 2) attention: reduce partials (64 hg2, contiguous) + trunk + 4 heads.
// ===========================================================================
__global__ __launch_bounds__(512) void attn3(
    const float* __restrict__ partial, const float* __restrict__ prep_w,
    const float* __restrict__ bn_g, const float* __restrict__ bn_b,
    const float* __restrict__ bn_m, const float* __restrict__ bn_v,
    const float* __restrict__ fc_sp_w, const float* __restrict__ fc_sp_b,
    const float* __restrict__ fc_ch_w, const float* __restrict__ fc_ch_b,
    const float* __restrict__ fc_f_w,  const float* __restrict__ fc_f_b,
    const float* __restrict__ fc_k_w,  const float* __restrict__ fc_k_b,
    float* __restrict__ sp, float* __restrict__ cha,
    float* __restrict__ fa, float* __restrict__ ka) {
    __shared__ float pooled_s[NB * CI];
    __shared__ float att_s[NB * CA];
    const int tid = threadIdx.x;
    const float scale = 1.f / (HH * WW);
    #pragma unroll
    for (int i = 0; i < 4; ++i) {
        const int e = tid + 512 * i;
        const float4* pp = (const float4*)(partial + (size_t)e * 64);
        float s = 0.f;
        #pragma unroll
        for (int j = 0; j < 16; ++j) { float4 v = pp[j]; s += v.x + v.y + v.z + v.w; }
        pooled_s[e] = s;
    }
    __syncthreads();
    const int b = tid >> 4, a = tid & 15;
    {
        float s = 0.f;
        const float* pv = pooled_s + b * CI;
        #pragma unroll
        for (int c = 0; c < CI; ++c) s += pv[c] * prep_w[a * CI + c];
        s = (s * scale - bn_m[a]) * rsqrtf(bn_v[a] + EPSBN) * bn_g[a] + bn_b[a];
        att_s[b * CA + a] = fmaxf(s, 0.f);
    }
    __syncthreads();
    float av[CA];
    #pragma unroll
    for (int i = 0; i < CA; ++i) av[i] = att_s[b * CA + i];

    const int j = a;
    if (j < 9) {
        float s = fc_sp_b[j];
        #pragma unroll
        for (int i = 0; i < CA; ++i) s += av[i] * fc_sp_w[j * CA + i];
        sp[b * 9 + j] = 1.f / (1.f + expf(-s));
    }
    #pragma unroll
    for (int t = 0; t < 4; ++t) {
        const int c = j * 4 + t;
        float s1 = fc_ch_b[c], s2 = fc_f_b[c];
        #pragma unroll
        for (int i = 0; i < CA; ++i) {
            s1 += av[i] * fc_ch_w[c * CA + i];
            s2 += av[i] * fc_f_w[c * CA + i];
        }
        cha[b * CI + c] = 1.f / (1.f + expf(-s1));
        fa[b * CO + c]  = 1.f / (1.f + expf(-s2));
    }
    if (j == 0) {
        float kv[NK], m = -1e30f;
        #pragma unroll
        for (int k = 0; k < NK; ++k) {
            float s = fc_k_b[k];
            #pragma unroll
            for (int i = 0; i < CA; ++i) s += av[i] * fc_k_w[k * CA + i];
            kv[k] = s; m = fmaxf(m, s);
        }
        float den = 0.f;
        #pragma unroll
        for (int k = 0; k < NK; ++k) { kv[k] = expf(kv[k] - m); den += kv[k]; }
        #pragma unroll
        for (int k = 0; k < NK; ++k) ka[b * NK + k] = kv[k] / den;
    }
}

// ===========================================================================
// 3) folded weights w2t[b][tap][o][i] bf16 (lanes = i: 128B-line writes)
// ===========================================================================
__global__ __launch_bounds__(256) void w2t2(const float* __restrict__ kernels,
                                            const float* __restrict__ sp,
                                            const float* __restrict__ cha,
                                            const float* __restrict__ fa,
                                            const float* __restrict__ ka,
                                            unsigned short* __restrict__ w2t) {
    const int bid = blockIdx.x;              // 32*16
    const int b  = bid >> 4;
    const int o  = (bid & 15) * 4 + (threadIdx.x >> 6);
    const int i  = threadIdx.x & 63;
    float kw[NK][9];
    #pragma unroll
    for (int k = 0; k < NK; ++k) {
        const float* kp = kernels + ((size_t)(k * CO + o) * CI + i) * 9;
        #pragma unroll
        for (int t = 0; t < 9; ++t) kw[k][t] = kp[t];
    }
    float kav[NK];
    #pragma unroll
    for (int k = 0; k < NK; ++k) kav[k] = ka[b * NK + k];
    const float base = cha[b * CI + i] * fa[b * CO + o];
    #pragma unroll
    for (int tap = 0; tap < 9; ++tap) {
        float s = 0.f;
        #pragma unroll
        for (int k = 0; k < NK; ++k) s += kav[k] * kw[k][tap];
        w2t[((size_t)(b * 9 + tap) * CO + o) * CI + i] = f2bf(s * sp[b * 9 + tap] * base);
    }
}

// ===========================================================================
// 4) All-LDS conv (mfma_f32_16x16x32_bf16). Block = 32co x 32col x 4row,
//    256 thr = 4 waves (og x colh); o-half (oh) is a GRID dim so the block's
//    full A-slice fits LDS. LDS 63488B: x-tile 6r x 34c x 64ci (26624B,
//    oct-XOR swizzled) + A-slice 9tap x 32o x 64ci (36864B, same swizzle).
//    Both staged via global_load_lds (62 chunks, one barrier). Hot loop:
//    54 ds_read_b128 + 72 MFMA per wave, ZERO global loads.
// ===========================================================================
__global__ __launch_bounds__(256, 2) void conv_lds(const unsigned short* __restrict__ xt,
                                                   const unsigned short* __restrict__ w2t,
                                                   const unsigned short* __restrict__ zeros,
                                                   float* __restrict__ out) {
    __shared__ __align__(16) unsigned char xs[63488];
    const int tid  = threadIdx.x;
    const int lane = tid & 63;
    const int wv   = tid >> 6;
    const int orig = blockIdx.x;
    const int bid  = (orig & 7) * 1024 + (orig >> 3);   // XCD swizzle (8192 = 8*1024)
    const int b    = bid >> 8;
    const int rem  = bid & 255;
    const int oh   = rem & 1;
    const int colg = (rem >> 1) & 3;
    const int hg   = rem >> 3;
    const int h0 = hg * 4;
    const int w0 = colg * 32;

    const unsigned short* xb = xt + (size_t)b * (HH * WW * CI);

    // ---- stage x: 6r x 34c x 8oct = 1632 16B-units (26 chunks, tail -> zeros)
    for (int chunk = wv; chunk < 26; chunk += 4) {
        const int unit = (chunk << 6) + lane;
        const int row  = (int)((unsigned)unit / 272u);
        const int rr   = unit - row * 272;
        const int col  = rr >> 3;
        const int q    = rr & 7;
        const int hh = h0 - 1 + row;
        const int wc = w0 - 1 + col;
        const unsigned short* g = zeros;
        if (unit < 1632 && (unsigned)hh < (unsigned)HH && (unsigned)wc < (unsigned)WW)
            g = xb + (((size_t)hh << 7) + (size_t)wc) * 64 + ((q ^ (col & 7)) << 3);
        gload_lds16(g, xs + (chunk << 10));
    }
    // ---- stage A-slice: 9tap x 32o x 8oct = 2304 units (36 chunks exact)
    const unsigned short* w2bb = w2t + (size_t)b * 36864 + oh * 2048;
    for (int chunk = wv; chunk < 36; chunk += 4) {
        const int unit = (chunk << 6) + lane;
        const int tap = unit >> 8;
        const int rr  = unit & 255;
        const int o   = rr >> 3;
        const int q   = rr & 7;
        const unsigned short* g = w2bb + tap * 4096 + o * 64 + ((q ^ (o & 7)) << 3);
        gload_lds16(g, xs + 26624 + (chunk << 10));
    }
    __syncthreads();

    const int cl = lane & 15;        // pixel col in 16 / o in 16
    const int kq = lane >> 4;        // k-quarter (8 ci)
    const int og   = wv & 1;
    const int colh = wv >> 1;        // 0..1

    f32x4 acc[4];
    #pragma unroll
    for (int t = 0; t < 4; ++t)
        #pragma unroll
        for (int e = 0; e < 4; ++e) acc[t][e] = 0.f;

    const unsigned char* abase = xs + 26624 + (og * 16 + cl) * 128;

    #pragma unroll
    for (int ks = 0; ks < 2; ++ks) {
        const int aoct = (((ks << 2) + kq) ^ (cl & 7)) << 4;
        #pragma unroll
        for (int v = 0; v < 3; ++v) {
            const int lcol = colh * 16 + cl + v;            // LDS col 0..33
            const int sw = ((ks << 2) + kq) ^ (lcol & 7);   // swizzled oct slot
            const unsigned char* bp = xs + (((lcol << 3) + sw) << 4);
            bf16x8 Bf[6];
            #pragma unroll
            for (int r = 0; r < 6; ++r) Bf[r] = *(const bf16x8*)(bp + r * 4352);
            #pragma unroll
            for (int u = 0; u < 3; ++u) {
                const bf16x8 A = *(const bf16x8*)(abase + (u * 3 + v) * 4096 + aoct);
                #pragma unroll
                for (int t = 0; t < 4; ++t)
                    acc[t] = __builtin_amdgcn_mfma_f32_16x16x32_bf16(A, Bf[t + u], acc[t], 0, 0, 0);
            }
        }
    }

    // ---- epilogue: o = oh*32 + og*16 + kq*4 + rg, col = w0 + colh*16 + cl
    #pragma unroll
    for (int t = 0; t < 4; ++t) {
        float* op = out + ((size_t)(b * CO + oh * 32 + og * 16 + kq * 4) * HH + h0 + t) * WW
                  + w0 + colh * 16 + cl;
        #pragma unroll
        for (int rg = 0; rg < 4; ++rg)
            op[(size_t)rg * (HH * WW)] = acc[t][rg];
    }
}

// ===========================================================================
extern "C" void kernel_launch(void* const* d_in, const int* in_sizes, int n_in,
                              void* d_out, int out_size, void* d_ws, size_t ws_size,
                              hipStream_t stream) {
    const float* x        = (const float*)d_in[0];
    const float* prep_w   = (const float*)d_in[1];
    const float* bn_g     = (const float*)d_in[2];
    const float* bn_b     = (const float*)d_in[3];
    const float* bn_m     = (const float*)d_in[4];
    const float* bn_v     = (const float*)d_in[5];
    const float* fc_sp_w  = (const float*)d_in[6];
    const float* fc_sp_b  = (const float*)d_in[7];
    const float* fc_ch_w  = (const float*)d_in[8];
    const float* fc_ch_b  = (const float*)d_in[9];
    const float* fc_f_w   = (const float*)d_in[10];
    const float* fc_f_b   = (const float*)d_in[11];
    const float* fc_k_w   = (const float*)d_in[12];
    const float* fc_k_b   = (const float*)d_in[13];
    const float* kernels  = (const float*)d_in[14];
    float* out = (float*)d_out;
    float* ws  = (float*)d_ws;

    float* zeros   = ws + WS_ZERO;
    float* cha     = ws + WS_CHA;
    float* fa      = ws + WS_FA;
    float* ka      = ws + WS_KA;
    float* sp      = ws + WS_SP;
    float* partial = ws + WS_PART;
    unsigned short* w2t = (unsigned short*)(ws + WS_W2T);
    unsigned short* xt  = (unsigned short*)(ws + WS_XT);

    transpose_pool<<<dim3(64, NB), 256, 0, stream>>>(x, xt, partial, zeros);
    attn3<<<1, 512, 0, stream>>>(partial, prep_w, bn_g, bn_b, bn_m, bn_v,
                                 fc_sp_w, fc_sp_b, fc_ch_w, fc_ch_b,
                                 fc_f_w, fc_f_b, fc_k_w, fc_k_b,
                                 sp, cha, fa, ka);
    w2t2<<<NB * 16, 256, 0, stream>>>(kernels, sp, cha, fa, ka, w2t);
    conv_lds<<<8192, 256, 0, stream>>>(xt, w2t, (const unsigned short*)zeros, out);
}

// Round 10
// 148.852 us; speedup vs baseline: 1.2417x; 1.0021x over previous
//
#include <hip/hip_runtime.h>
#include <math.h>

// Problem constants
#define NB 32
#define CI 64
#define CO 64
#define CA 16
#define NK 4
#define HH 128
#define WW 128
#define EPSBN 1e-5f

typedef __bf16 bf16x8 __attribute__((ext_vector_type(8)));
typedef float f32x4 __attribute__((ext_vector_type(4)));

__device__ inline unsigned short f2bf(float f) {
    union { float f; unsigned u; } c; c.f = f;
    return (unsigned short)((c.u + 0x7fffu + ((c.u >> 16) & 1u)) >> 16);
}

// packed 2xf32 -> 2xbf16 (lo = first arg), single VALU op
__device__ inline unsigned cvt_pk_bf16(float lo, float hi) {
    unsigned r;
    asm("v_cvt_pk_bf16_f32 %0, %1, %2" : "=v"(r) : "v"(lo), "v"(hi));
    return r;
}

__device__ inline void gload_lds16(const void* g, void* l) {
    __builtin_amdgcn_global_load_lds(
        (const __attribute__((address_space(1))) unsigned int*)g,
        (__attribute__((address_space(3))) unsigned int*)l, 16, 0, 0);
}

// Workspace layout (float offsets). Total 70.5 MB (proven available).
#define WS_ZERO  0              // 64 (zero page for OOB redirect)
#define WS_CHA   64             // 2048
#define WS_FA    2112           // 2048
#define WS_KA    4160           // 128
#define WS_SP    4288           // 288
#define WS_PART  8192           // 32*64*64 = 131072 used
#define WS_W2T   270336         // 1179648 ushorts
#define WS_XT    860160         // 33554432 ushorts

// ===========================================================================
// 1) Register transpose + pooled partials. Block = (hg2 of 2 rows, b),
//    256 thr: w4 = tid&31 (4 w each), rowsel = (tid>>5)&1, ciq = tid>>6
//    (16 ci). One wave load instr = 1024B contiguous (w4 x row-pair of one
//    plane). 16 float4 in flight/thread. Pack via v_cvt_pk_bf16_f32, store
//    8x uint4 (NHWC). Pool: shfl_xor over w4 + 0.5KB LDS.
// ===========================================================================
__global__ __launch_bounds__(256, 4) void transpose_pool(const float* __restrict__ x,
                                                         unsigned short* __restrict__ xt,
                                                         float* __restrict__ partial,
                                                         float* __restrict__ zeros) {
    __shared__ float redl[2][4][17];
    const int tid = threadIdx.x;
    const int hg2 = blockIdx.x;      // 0..63 (2 rows each)
    const int b   = blockIdx.y;
    const int w4     = tid & 31;
    const int rowsel = (tid >> 5) & 1;
    const int ciq    = tid >> 6;     // wave id: ci quarter (uniform per wave)
    const int h  = hg2 * 2 + rowsel;
    const int ci0 = ciq * 16;

    if (hg2 == 0 && b == 0 && tid < 64) zeros[tid] = 0.f;   // zero page for conv

    // 16 float4 loads (each wave instr: 64 lanes x 16B = 1KB contiguous)
    float4 v[16];
    const float* xp = x + ((size_t)(b * CI + ci0) * HH + h) * WW + w4 * 4;
    #pragma unroll
    for (int i = 0; i < 16; ++i) v[i] = *(const float4*)(xp + (size_t)i * (HH * WW));

    float s16[16];
    #pragma unroll
    for (int i = 0; i < 16; ++i) s16[i] = v[i].x + v[i].y + v[i].z + v[i].w;

    // pack + store: per w (4), 8 cvt_pk -> 32B (16 ci) -> 2 uint4
    unsigned short* dbase = xt + ((size_t)(b * HH + h) * WW + w4 * 4) * CI + ci0;
    #pragma unroll
    for (int e = 0; e < 4; ++e) {
        float ve[16];
        #pragma unroll
        for (int i = 0; i < 16; ++i)
            ve[i] = (e == 0) ? v[i].x : (e == 1) ? v[i].y : (e == 2) ? v[i].z : v[i].w;
        unsigned q[8];
        #pragma unroll
        for (int j = 0; j < 8; ++j) q[j] = cvt_pk_bf16(ve[2 * j], ve[2 * j + 1]);
        uint4* dst = (uint4*)(dbase + (size_t)e * CI);
        dst[0] = make_uint4(q[0], q[1], q[2], q[3]);
        dst[1] = make_uint4(q[4], q[5], q[6], q[7]);
    }

    // pool reduce over the 32 w4 lanes (within rowsel half)
    #pragma unroll
    for (int mask = 1; mask <= 16; mask <<= 1)
        #pragma unroll
        for (int i = 0; i < 16; ++i) s16[i] += __shfl_xor(s16[i], mask, 64);
    if (w4 == 0) {
        #pragma unroll
        for (int i = 0; i < 16; ++i) redl[rowsel][ciq][i] = s16[i];
    }
    __syncthreads();
    if (tid < 64)
        partial[((size_t)b * CI + tid) * 64 + hg2] =
            redl[0][tid >> 4][tid & 15] + redl[1][tid >> 4][tid & 15];
}

// ===========================================================================
// 2) attention: reduce partials (64 hg2, contiguous) + trunk + 4 heads.
// ===========================================================================
__global__ __launch_bounds__(512) void attn3(
    const float* __restrict__ partial, const float* __restrict__ prep_w,
    const float* __restrict__ bn_g, const float* __restrict__ bn_b,
    const float* __restrict__ bn_m, const float* __restrict__ bn_v,
    const float* __restrict__ fc_sp_w, const float* __restrict__ fc_sp_b,
    const float* __restrict__ fc_ch_w, const float* __restrict__ fc_ch_b,
    const float* __restrict__ fc_f_w,  const float* __restrict__ fc_f_b,
    const float* __restrict__ fc_k_w,  const float* __restrict__ fc_k_b,
    float* __restrict__ sp, float* __restrict__ cha,
    float* __restrict__ fa, float* __restrict__ ka) {
    __shared__ float pooled_s[NB * CI];
    __shared__ float att_s[NB * CA];
    const int tid = threadIdx.x;
    const float scale = 1.f / (HH * WW);
    #pragma unroll
    for (int i = 0; i < 4; ++i) {
        const int e = tid + 512 * i;
        const float4* pp = (const float4*)(partial + (size_t)e * 64);
        float s = 0.f;
        #pragma unroll
        for (int j = 0; j < 16; ++j) { float4 v = pp[j]; s += v.x + v.y + v.z + v.w; }
        pooled_s[e] = s;
    }
    __syncthreads();
    const int b = tid >> 4, a = tid & 15;
    {
        float s = 0.f;
        const float* pv = pooled_s + b * CI;
        #pragma unroll
        for (int c = 0; c < CI; ++c) s += pv[c] * prep_w[a * CI + c];
        s = (s * scale - bn_m[a]) * rsqrtf(bn_v[a] + EPSBN) * bn_g[a] + bn_b[a];
        att_s[b * CA + a] = fmaxf(s, 0.f);
    }
    __syncthreads();
    float av[CA];
    #pragma unroll
    for (int i = 0; i < CA; ++i) av[i] = att_s[b * CA + i];

    const int j = a;
    if (j < 9) {
        float s = fc_sp_b[j];
        #pragma unroll
        for (int i = 0; i < CA; ++i) s += av[i] * fc_sp_w[j * CA + i];
        sp[b * 9 + j] = 1.f / (1.f + expf(-s));
    }
    #pragma unroll
    for (int t = 0; t < 4; ++t) {
        const int c = j * 4 + t;
        float s1 = fc_ch_b[c], s2 = fc_f_b[c];
        #pragma unroll
        for (int i = 0; i < CA; ++i) {
            s1 += av[i] * fc_ch_w[c * CA + i];
            s2 += av[i] * fc_f_w[c * CA + i];
        }
        cha[b * CI + c] = 1.f / (1.f + expf(-s1));
        fa[b * CO + c]  = 1.f / (1.f + expf(-s2));
    }
    if (j == 0) {
        float kv[NK], m = -1e30f;
        #pragma unroll
        for (int k = 0; k < NK; ++k) {
            float s = fc_k_b[k];
            #pragma unroll
            for (int i = 0; i < CA; ++i) s += av[i] * fc_k_w[k * CA + i];
            kv[k] = s; m = fmaxf(m, s);
        }
        float den = 0.f;
        #pragma unroll
        for (int k = 0; k < NK; ++k) { kv[k] = expf(kv[k] - m); den += kv[k]; }
        #pragma unroll
        for (int k = 0; k < NK; ++k) ka[b * NK + k] = kv[k] / den;
    }
}

// ===========================================================================
// 3) folded weights w2t[b][tap][o][i] bf16 (lanes = i: 128B-line writes)
// ===========================================================================
__global__ __launch_bounds__(256) void w2t2(const float* __restrict__ kernels,
                                            const float* __restrict__ sp,
                                            const float* __restrict__ cha,
                                            const float* __restrict__ fa,
                                            const float* __restrict__ ka,
                                            unsigned short* __restrict__ w2t) {
    const int bid = blockIdx.x;              // 32*16
    const int b  = bid >> 4;
    const int o  = (bid & 15) * 4 + (threadIdx.x >> 6);
    const int i  = threadIdx.x & 63;
    float kw[NK][9];
    #pragma unroll
    for (int k = 0; k < NK; ++k) {
        const float* kp = kernels + ((size_t)(k * CO + o) * CI + i) * 9;
        #pragma unroll
        for (int t = 0; t < 9; ++t) kw[k][t] = kp[t];
    }
    float kav[NK];
    #pragma unroll
    for (int k = 0; k < NK; ++k) kav[k] = ka[b * NK + k];
    const float base = cha[b * CI + i] * fa[b * CO + o];
    #pragma unroll
    for (int tap = 0; tap < 9; ++tap) {
        float s = 0.f;
        #pragma unroll
        for (int k = 0; k < NK; ++k) s += kav[k] * kw[k][tap];
        w2t[((size_t)(b * 9 + tap) * CO + o) * CI + i] = f2bf(s * sp[b * 9 + tap] * base);
    }
}

// ===========================================================================
// 4) All-LDS conv with ks-phase A restage (mfma_f32_16x16x32_bf16).
//    Block = 64co x 32col x 4row, 256 thr / 4 waves = (cohalf x colh).
//    LDS 63488B: x-tile 6r x 34c x 64ci (26624B, oct-XOR swizzled src) +
//    A-phase 9tap x [q 4][o 64] (36864B; q-quartile layout -> per-16-lane
//    phase reads are 2-way = free, no swizzle).
//    Flow: stage(x + A-ks0) -> bar -> compute ks0 -> bar -> stage A-ks1 ->
//    bar -> compute ks1. x staged ONCE (vs r9's oh-duplicated staging).
// ===========================================================================
__global__ __launch_bounds__(256, 2) void conv_lds(const unsigned short* __restrict__ xt,
                                                   const unsigned short* __restrict__ w2t,
                                                   const unsigned short* __restrict__ zeros,
                                                   float* __restrict__ out) {
    __shared__ __align__(16) unsigned char xs[63488];
    const int tid  = threadIdx.x;
    const int lane = tid & 63;
    const int wv   = tid >> 6;
    const int orig = blockIdx.x;
    const int bid  = (orig & 7) * 512 + (orig >> 3);    // XCD swizzle (4096 = 8*512)
    const int b    = bid >> 7;
    const int rem  = bid & 127;
    const int colg = rem & 3;
    const int hg   = rem >> 2;
    const int h0 = hg * 4;
    const int w0 = colg * 32;

    const unsigned short* xb = xt + (size_t)b * (HH * WW * CI);
    const unsigned short* w2base = w2t + (size_t)b * 36864;

    // ---- stage x: 6r x 34c x 8oct = 1632 16B-units (26 chunks, tail -> zeros)
    for (int chunk = wv; chunk < 26; chunk += 4) {
        const int unit = (chunk << 6) + lane;
        const int row  = (int)((unsigned)unit / 272u);
        const int rr   = unit - row * 272;
        const int col  = rr >> 3;
        const int q    = rr & 7;
        const int hh = h0 - 1 + row;
        const int wc = w0 - 1 + col;
        const unsigned short* g = zeros;
        if (unit < 1632 && (unsigned)hh < (unsigned)HH && (unsigned)wc < (unsigned)WW)
            g = xb + (((size_t)hh << 7) + (size_t)wc) * 64 + ((q ^ (col & 7)) << 3);
        gload_lds16(g, xs + (chunk << 10));
    }
    // ---- stage A ks=0: chunk = tap*4 + q; lanes = o (64). dest [tap][q][o]
    for (int chunk = wv; chunk < 36; chunk += 4) {
        const int tap = chunk >> 2;
        const int q   = chunk & 3;
        const unsigned short* g = w2base + tap * 4096 + lane * 64 + q * 8;
        gload_lds16(g, xs + 26624 + (chunk << 10));
    }
    __syncthreads();

    const int cl = lane & 15;        // pixel col in 16 / o in 16
    const int kq = lane >> 4;        // k-quarter within phase (8 ci)
    const int cohalf = wv & 1;
    const int colh   = wv >> 1;      // 0..1

    f32x4 acc[2][4];
    #pragma unroll
    for (int og = 0; og < 2; ++og)
        #pragma unroll
        for (int t = 0; t < 4; ++t)
            #pragma unroll
            for (int e = 0; e < 4; ++e) acc[og][t][e] = 0.f;

    const unsigned char* abase = xs + 26624 + kq * 1024 + (cohalf * 32 + cl) * 16;

    // ---- ks = 0 compute (72 MFMA/wave)
    #pragma unroll
    for (int v = 0; v < 3; ++v) {
        const int lcol = colh * 16 + cl + v;            // LDS col 0..33
        const int sw = kq ^ (lcol & 7);                 // ks=0 oct
        const unsigned char* bp = xs + (((lcol << 3) + sw) << 4);
        bf16x8 Bf[6];
        #pragma unroll
        for (int r = 0; r < 6; ++r) Bf[r] = *(const bf16x8*)(bp + r * 4352);
        #pragma unroll
        for (int u = 0; u < 3; ++u) {
            const unsigned char* ap = abase + (u * 3 + v) * 4096;
            const bf16x8 A0 = *(const bf16x8*)(ap);
            const bf16x8 A1 = *(const bf16x8*)(ap + 256);     // og=1: +16 o
            #pragma unroll
            for (int t = 0; t < 4; ++t)
                acc[0][t] = __builtin_amdgcn_mfma_f32_16x16x32_bf16(A0, Bf[t + u], acc[0][t], 0, 0, 0);
            #pragma unroll
            for (int t = 0; t < 4; ++t)
                acc[1][t] = __builtin_amdgcn_mfma_f32_16x16x32_bf16(A1, Bf[t + u], acc[1][t], 0, 0, 0);
        }
    }
    __syncthreads();

    // ---- restage A ks=1 over the same region
    for (int chunk = wv; chunk < 36; chunk += 4) {
        const int tap = chunk >> 2;
        const int q   = chunk & 3;
        const unsigned short* g = w2base + tap * 4096 + lane * 64 + 32 + q * 8;
        gload_lds16(g, xs + 26624 + (chunk << 10));
    }
    __syncthreads();

    // ---- ks = 1 compute
    #pragma unroll
    for (int v = 0; v < 3; ++v) {
        const int lcol = colh * 16 + cl + v;
        const int sw = (4 + kq) ^ (lcol & 7);           // ks=1 oct
        const unsigned char* bp = xs + (((lcol << 3) + sw) << 4);
        bf16x8 Bf[6];
        #pragma unroll
        for (int r = 0; r < 6; ++r) Bf[r] = *(const bf16x8*)(bp + r * 4352);
        #pragma unroll
        for (int u = 0; u < 3; ++u) {
            const unsigned char* ap = abase + (u * 3 + v) * 4096;
            const bf16x8 A0 = *(const bf16x8*)(ap);
            const bf16x8 A1 = *(const bf16x8*)(ap + 256);
            #pragma unroll
            for (int t = 0; t < 4; ++t)
                acc[0][t] = __builtin_amdgcn_mfma_f32_16x16x32_bf16(A0, Bf[t + u], acc[0][t], 0, 0, 0);
            #pragma unroll
            for (int t = 0; t < 4; ++t)
                acc[1][t] = __builtin_amdgcn_mfma_f32_16x16x32_bf16(A1, Bf[t + u], acc[1][t], 0, 0, 0);
        }
    }

    // ---- epilogue: o = cohalf*32 + og*16 + kq*4 + rg, col = w0 + colh*16 + cl
    #pragma unroll
    for (int og = 0; og < 2; ++og)
        #pragma unroll
        for (int t = 0; t < 4; ++t) {
            float* op = out + ((size_t)(b * CO + cohalf * 32 + og * 16 + kq * 4) * HH + h0 + t) * WW
                      + w0 + colh * 16 + cl;
            #pragma unroll
            for (int rg = 0; rg < 4; ++rg)
                op[(size_t)rg * (HH * WW)] = acc[og][t][rg];
        }
}

// ===========================================================================
extern "C" void kernel_launch(void* const* d_in, const int* in_sizes, int n_in,
                              void* d_out, int out_size, void* d_ws, size_t ws_size,
                              hipStream_t stream) {
    const float* x        = (const float*)d_in[0];
    const float* prep_w   = (const float*)d_in[1];
    const float* bn_g     = (const float*)d_in[2];
    const float* bn_b     = (const float*)d_in[3];
    const float* bn_m     = (const float*)d_in[4];
    const float* bn_v     = (const float*)d_in[5];
    const float* fc_sp_w  = (const float*)d_in[6];
    const float* fc_sp_b  = (const float*)d_in[7];
    const float* fc_ch_w  = (const float*)d_in[8];
    const float* fc_ch_b  = (const float*)d_in[9];
    const float* fc_f_w   = (const float*)d_in[10];
    const float* fc_f_b   = (const float*)d_in[11];
    const float* fc_k_w   = (const float*)d_in[12];
    const float* fc_k_b   = (const float*)d_in[13];
    const float* kernels  = (const float*)d_in[14];
    float* out = (float*)d_out;
    float* ws  = (float*)d_ws;

    float* zeros   = ws + WS_ZERO;
    float* cha     = ws + WS_CHA;
    float* fa      = ws + WS_FA;
    float* ka      = ws + WS_KA;
    float* sp      = ws + WS_SP;
    float* partial = ws + WS_PART;
    unsigned short* w2t = (unsigned short*)(ws + WS_W2T);
    unsigned short* xt  = (unsigned short*)(ws + WS_XT);

    transpose_pool<<<dim3(64, NB), 256, 0, stream>>>(x, xt, partial, zeros);
    attn3<<<1, 512, 0, stream>>>(partial, prep_w, bn_g, bn_b, bn_m, bn_v,
                                 fc_sp_w, fc_sp_b, fc_ch_w, fc_ch_b,
                                 fc_f_w, fc_f_b, fc_k_w, fc_k_b,
                                 sp, cha, fa, ka);
    w2t2<<<NB * 16, 256, 0, stream>>>(kernels, sp, cha, fa, ka, w2t);
    conv_lds<<<4096, 256, 0, stream>>>(xt, w2t, (const unsigned short*)zeros, out);
}